// Round 11
// baseline (140.357 us; speedup 1.0000x reference)
//
#include <hip/hip_runtime.h>

typedef float f32x4 __attribute__((ext_vector_type(4)));
typedef int   i32x4 __attribute__((ext_vector_type(4)));
typedef int   i32x8 __attribute__((ext_vector_type(8)));

#define FP8_MAX 448.0f
#define AS1 __attribute__((address_space(1)))
#define AS3 __attribute__((address_space(3)))

// ---------------------------------------------------------------------------
// Activation quant: per (row, 128-elem K-block): s = max|x|/448, q = fp8(x/s).
// Writes xq [M][K] fp8 bytes and xst TRANSPOSED scales [K/128][M].
// ---------------------------------------------------------------------------
__global__ __launch_bounds__(256) void act_quant_k(const float* __restrict__ x,
                                                   unsigned char* __restrict__ xq,
                                                   float* __restrict__ xst,
                                                   int M, int K) {
    const int t   = threadIdx.x;
    const int qb  = blockIdx.x * 8 + (t >> 5);   // global 128-block id
    const int l32 = t & 31;
    const int row = qb >> 5;                     // K/128 == 32 blocks per row
    const int kb  = qb & 31;
    const size_t base = (size_t)row * K + (size_t)kb * 128 + (size_t)l32 * 4;

    float4 v = *(const float4*)(x + base);
    float am = fmaxf(fmaxf(fabsf(v.x), fabsf(v.y)), fmaxf(fabsf(v.z), fabsf(v.w)));
#pragma unroll
    for (int off = 1; off < 32; off <<= 1)
        am = fmaxf(am, __shfl_xor(am, off, 64));

    const float s = am / FP8_MAX;                // fp32 IEEE div, matches reference
    const float q0 = v.x / s, q1 = v.y / s, q2 = v.z / s, q3 = v.w / s;
    int p = __builtin_amdgcn_cvt_pk_fp8_f32(q0, q1, 0, false);
    p     = __builtin_amdgcn_cvt_pk_fp8_f32(q2, q3, p, true);
    *(int*)(xq + base) = p;
    if (l32 == 0) xst[(size_t)kb * M + row] = s;
}

// ---------------------------------------------------------------------------
// Weight fp32 -> fp8 byte conversion (values already on the e4m3 grid: exact).
// ---------------------------------------------------------------------------
__global__ __launch_bounds__(256) void wq_cvt_k(const float* __restrict__ w,
                                                unsigned char* __restrict__ wq) {
    const size_t i = ((size_t)blockIdx.x * 256 + threadIdx.x) * 4;
    float4 v = *(const float4*)(w + i);
    int p = __builtin_amdgcn_cvt_pk_fp8_f32(v.x, v.y, 0, false);
    p     = __builtin_amdgcn_cvt_pk_fp8_f32(v.z, v.w, p, true);
    *(int*)(wq + i) = p;
}

// ---------------------------------------------------------------------------
// 256x256-tile fp8 block-dequant GEMM on mfma_scale_f32_16x16x128_f8f6f4
// (HW scales = 1.0 -> exact fp8 dot over K=128 = one quant block).
// 8 waves (2Mx4N), per-wave 128x64 = 8m x 4n frags; 32 mfma_scale per K-step.
// K-step = 128; double-buffered LDS; one vmcnt(0)+barrier per K-step.
//
// R11: quadrant software pipeline. The step is split into 4 quadrants
// (2 m-frags each); reads for quadrant q+1 are ISSUED before the MFMA
// cluster of quadrant q (ping-pong register slots, constant-indexed), so
// LDS-read service of q+1 hides under MFMA of q. Order:
//   pb(8 reads) -> ISSUE(q0) -> ISSUE(q1) -> stage DMA -> MFMA(q0) ->
//   ISSUE(q2) -> MFMA(q1) -> ISSUE(q3) -> MFMA(q2) -> MFMA(q3) ->
//   vmcnt(0) -> barrier.
// Fold accM[m][n] += q*(a_s[m]*w_s) after each quadrant's MFMAs (same
// per-element fold order as R10 -> bit-identical output).
//
// LDS layout: [256 rows][128 B] per operand per buffer. Swizzle (both-sides,
// rule 21): phys_col16 = col16 ^ (row & 7); staging pre-swizzles the GLOBAL
// source column (LDS dest linear), ds_read applies the same XOR.
// ---------------------------------------------------------------------------
__global__ __launch_bounds__(512, 2) void gemm_fp8_blk(
    const unsigned char* __restrict__ Aq,   // [M][K] fp8
    const unsigned char* __restrict__ Bq,   // [N][K] fp8
    const float* __restrict__ xst,          // [K/128][M] act scales (transposed)
    const float* __restrict__ wsc,          // [N/128][K/128] weight scales
    float* __restrict__ C, int M, int N, int K) {
    __shared__ unsigned char As[2][32768];  // [buf][256 rows x 128 B]
    __shared__ unsigned char Bs[2][32768];
    __shared__ float Ss[2][256];            // act scales, 2-slot ring

    const int t    = threadIdx.x;
    const int lane = t & 63;
    const int wave = t >> 6;            // 0..7
    const int wr   = wave >> 2;         // wave row (0..1) -> rows wr*128
    const int wc   = wave & 3;          // wave col (0..3) -> cols wc*64
    const int bm   = blockIdx.y * 256;
    const int bn   = blockIdx.x * 256;

    // staging: 512 threads x 16B = 8KB = 64 rows x 128B per issue; 4/op/K-step
    const int srow   = t >> 3;          // 0..63
    const int scolsw = (((t & 7) ^ ((t >> 3) & 7)) << 4);   // pre-swizzled src col
    const unsigned char* gA = Aq + (size_t)(bm + srow) * K + scolsw;
    const unsigned char* gB = Bq + (size_t)(bn + srow) * K + scolsw;
    const float* gS = xst + bm + ((wave & 3) << 6) + lane;  // + kb*M per stage
    const int ldsoff = wave << 10;      // wave-uniform LDS base (+ lane*16 by HW)
    const int sSoff  = (wave & 3) << 8; // waves 4-7 duplicate 0-3 (same data)

    // fragment read addressing (swizzled): lane holds k = g*32 + 0..31
    const int r15 = lane & 15;
    const int g   = lane >> 4;                    // k-chunk 0..3
    const int km  = r15 & 7;                      // row swizzle key
    const int pc0 = (((2 * g) ^ km) << 4);        // first 16B unit
    const int pc1 = pc0 ^ 16;                     // second 16B unit
    const int aBase = (wr * 128 + r15) << 7;      // + m*2048 per frag
    const int bBase = (wc * 64 + r15) << 7;       // + n*2048 per frag
    const int ssB   = wr * 128 + (g << 2);        // float idx into Ss slot

    const float* wscp = wsc + (((bn + wc * 64) >> 7) << 5);  // wave-uniform row

#define STG_A(BUF, KB, I)                                                       \
    __builtin_amdgcn_global_load_lds(                                           \
        (const AS1 void*)(gA + (size_t)(I) * 64 * K + ((size_t)(KB) << 7)),     \
        (AS3 void*)(&As[BUF][0] + (I) * 8192 + ldsoff), 16, 0, 0)
#define STG_B(BUF, KB, I)                                                       \
    __builtin_amdgcn_global_load_lds(                                           \
        (const AS1 void*)(gB + (size_t)(I) * 64 * K + ((size_t)(KB) << 7)),     \
        (AS3 void*)(&Bs[BUF][0] + (I) * 8192 + ldsoff), 16, 0, 0)
#define STG_S(KB)                                                               \
    __builtin_amdgcn_global_load_lds(                                           \
        (const AS1 void*)(gS + (size_t)(KB) * M),                               \
        (AS3 void*)((unsigned char*)&Ss[(KB) & 1][0] + sSoff), 4, 0, 0)
#define VMCNT0() asm volatile("s_waitcnt vmcnt(0)" ::: "memory")

#define RD8(PTR, RB) ({                                                         \
    i32x4 lo_ = *(const i32x4*)((PTR) + (RB) + pc0);                            \
    i32x4 hi_ = *(const i32x4*)((PTR) + (RB) + pc1);                            \
    __builtin_shufflevector(lo_, hi_, 0, 1, 2, 3, 4, 5, 6, 7); })

// issue quadrant QQ's A-frag + raw-scale reads into ping-pong slot SLOT
#define ISSUE_Q(SLOT, QQ) do {                                                  \
    pa[SLOT][0]  = RD8(ap, aBase + ((2 * (QQ)) << 11));                         \
    pa[SLOT][1]  = RD8(ap, aBase + ((2 * (QQ) + 1) << 11));                     \
    scr[SLOT][0] = *(const f32x4*)(sp + ssB + ((2 * (QQ)) << 4));               \
    scr[SLOT][1] = *(const f32x4*)(sp + ssB + ((2 * (QQ) + 1) << 4));           \
} while (0)

// MFMA + fold quadrant QQ from slot SLOT
#define MFMA_Q(SLOT, QQ) do {                                                   \
    f32x4 q_[2][4];                                                             \
    __builtin_amdgcn_s_setprio(1);                                              \
    _Pragma("unroll")                                                           \
    for (int n = 0; n < 4; ++n) {                                               \
        q_[0][n] = __builtin_amdgcn_mfma_scale_f32_16x16x128_f8f6f4(            \
            pa[SLOT][0], pb[n], z4, 0, 0, 0, 0x7F7F7F7F, 0, 0x7F7F7F7F);        \
        q_[1][n] = __builtin_amdgcn_mfma_scale_f32_16x16x128_f8f6f4(            \
            pa[SLOT][1], pb[n], z4, 0, 0, 0, 0x7F7F7F7F, 0, 0x7F7F7F7F);        \
    }                                                                           \
    __builtin_amdgcn_s_setprio(0);                                              \
    {                                                                           \
        f32x4 s0_ = scr[SLOT][0] * wsv, s1_ = scr[SLOT][1] * wsv;               \
        _Pragma("unroll")                                                       \
        for (int n = 0; n < 4; ++n) {                                           \
            accM[2 * (QQ)][n]     += q_[0][n] * s0_;                            \
            accM[2 * (QQ) + 1][n] += q_[1][n] * s1_;                            \
        }                                                                       \
    }                                                                           \
} while (0)

    f32x4 accM[8][4] = {};
    const f32x4 z4 = {0.f, 0.f, 0.f, 0.f};

    // prologue: stage K-step 0 (scale + 4A + 4B), drain, sync.
    STG_S(0);
#pragma unroll
    for (int i = 0; i < 4; ++i) { STG_A(0, 0, i); STG_B(0, 0, i); }
    VMCNT0();
    __builtin_amdgcn_s_barrier();
    asm volatile("" ::: "memory");

#pragma unroll 1
    for (int kb = 0; kb < 32; ++kb) {
        const int buf = kb & 1;
        const float wsv = wscp[kb];
        const unsigned char* ap = &As[buf][0];
        const unsigned char* bp = &Bs[buf][0];
        const float* sp = &Ss[buf][0];

        i32x8 pb[4];
        i32x8 pa[2][2];
        f32x4 scr[2][2];

#pragma unroll
        for (int n = 0; n < 4; ++n) pb[n] = RD8(bp, bBase + (n << 11));
        ISSUE_Q(0, 0);
        ISSUE_Q(1, 1);
        // stage next K-step (8 data + 1 scale); lands under this step's compute
        if (kb < 31) {
            STG_S(kb + 1);
#pragma unroll
            for (int i = 0; i < 4; ++i) { STG_A(buf ^ 1, kb + 1, i); STG_B(buf ^ 1, kb + 1, i); }
        }
        MFMA_Q(0, 0);
        ISSUE_Q(0, 2);
        MFMA_Q(1, 1);
        ISSUE_Q(1, 3);
        MFMA_Q(0, 2);
        MFMA_Q(1, 3);

        VMCNT0();                      // staged loads for kb+1 have landed
        __builtin_amdgcn_s_barrier();  // everyone done reading buf
        asm volatile("" ::: "memory");
    }

    // C write: row = g*4 + reg within frag, col = r15 (verified C/D layout)
    const int cm = bm + wr * 128 + (g << 2);
    const int cn = bn + wc * 64 + r15;
#pragma unroll
    for (int m = 0; m < 8; ++m)
#pragma unroll
        for (int n = 0; n < 4; ++n) {
            float* cp = C + (size_t)(cm + m * 16) * N + (cn + n * 16);
#pragma unroll
            for (int r = 0; r < 4; ++r) cp[(size_t)r * N] = accM[m][n][r];
        }
#undef STG_A
#undef STG_B
#undef STG_S
#undef VMCNT0
#undef RD8
#undef ISSUE_Q
#undef MFMA_Q
}

extern "C" void kernel_launch(void* const* d_in, const int* in_sizes, int n_in,
                              void* d_out, int out_size, void* d_ws, size_t ws_size,
                              hipStream_t stream) {
    const float* x   = (const float*)d_in[0];   // [4096][4096] fp32
    const float* wqf = (const float*)d_in[1];   // [4096][4096] fp32 (fp8-grid values)
    const float* wsc = (const float*)d_in[2];   // [32][32] fp32
    float* out = (float*)d_out;

    const int M = 4096, N = 4096, K = 4096;

    unsigned char* xq  = (unsigned char*)d_ws;                       // 16 MB
    unsigned char* wq8 = (unsigned char*)d_ws + (size_t)M * K;       // 16 MB
    float* xst = (float*)((unsigned char*)d_ws + (size_t)M * K + (size_t)N * K); // 512 KB

    act_quant_k<<<M * (K / 128) / 8, 256, 0, stream>>>(x, xq, xst, M, K);
    wq_cvt_k<<<(N / 4) * (K / 256), 256, 0, stream>>>(wqf, wq8);
    dim3 grid(N / 256, M / 256);
    gemm_fp8_blk<<<grid, 512, 0, stream>>>(xq, wq8, xst, wsc, out, M, N, K);
}

// Round 12
// 111.676 us; speedup vs baseline: 1.2568x; 1.2568x over previous
//
#include <hip/hip_runtime.h>

typedef float f32x4 __attribute__((ext_vector_type(4)));
typedef int   i32x4 __attribute__((ext_vector_type(4)));
typedef int   i32x8 __attribute__((ext_vector_type(8)));

#define FP8_MAX 448.0f
#define AS1 __attribute__((address_space(1)))
#define AS3 __attribute__((address_space(3)))

// ---------------------------------------------------------------------------
// Activation quant: per (row, 128-elem K-block): s = max|x|/448, q = fp8(x/s).
// Writes xq [M][K] fp8 bytes and xst TRANSPOSED scales [K/128][M].
// ---------------------------------------------------------------------------
__global__ __launch_bounds__(256) void act_quant_k(const float* __restrict__ x,
                                                   unsigned char* __restrict__ xq,
                                                   float* __restrict__ xst,
                                                   int M, int K) {
    const int t   = threadIdx.x;
    const int qb  = blockIdx.x * 8 + (t >> 5);   // global 128-block id
    const int l32 = t & 31;
    const int row = qb >> 5;                     // K/128 == 32 blocks per row
    const int kb  = qb & 31;
    const size_t base = (size_t)row * K + (size_t)kb * 128 + (size_t)l32 * 4;

    float4 v = *(const float4*)(x + base);
    float am = fmaxf(fmaxf(fabsf(v.x), fabsf(v.y)), fmaxf(fabsf(v.z), fabsf(v.w)));
#pragma unroll
    for (int off = 1; off < 32; off <<= 1)
        am = fmaxf(am, __shfl_xor(am, off, 64));

    const float s = am / FP8_MAX;                // fp32 IEEE div, matches reference
    const float q0 = v.x / s, q1 = v.y / s, q2 = v.z / s, q3 = v.w / s;
    int p = __builtin_amdgcn_cvt_pk_fp8_f32(q0, q1, 0, false);
    p     = __builtin_amdgcn_cvt_pk_fp8_f32(q2, q3, p, true);
    *(int*)(xq + base) = p;
    if (l32 == 0) xst[(size_t)kb * M + row] = s;
}

// ---------------------------------------------------------------------------
// Weight fp32 -> fp8 byte conversion (values already on the e4m3 grid: exact).
// ---------------------------------------------------------------------------
__global__ __launch_bounds__(256) void wq_cvt_k(const float* __restrict__ w,
                                                unsigned char* __restrict__ wq) {
    const size_t i = ((size_t)blockIdx.x * 256 + threadIdx.x) * 4;
    float4 v = *(const float4*)(w + i);
    int p = __builtin_amdgcn_cvt_pk_fp8_f32(v.x, v.y, 0, false);
    p     = __builtin_amdgcn_cvt_pk_fp8_f32(v.z, v.w, p, true);
    *(int*)(wq + i) = p;
}

// ---------------------------------------------------------------------------
// 128x128-tile fp8 block-dequant GEMM on mfma_scale_f32_16x16x128_f8f6f4
// (HW e8m0 scales = 1.0 -> exact fp8 dot over K=128 = one quant block).
// R12: R4's occupancy structure x R10's instruction. 4 waves (2x2), per-wave
// 64x64 = 4m x 4n frags; 16 mfma_scale per K-step (K-step = 128 = one quant
// block). Double-buffered LDS = 66.5 KB -> TWO independent blocks resident
// per CU: their barrier groups interleave, so one block's lgkm/vmcnt/barrier
// stalls are filled by the other block's MFMAs (m114 TLP mechanism, the R4
// 35%-util structure). Simple R10 step order (reads -> stage DMA -> MFMA +
// fold -> vmcnt(0) -> barrier); no intra-block pipelining (R11 disproved).
// Fold once per frag per K-step: accM[m][n] += q * (a_s[m] * w_s).
//
// LDS layout: [128 rows][128 B] per operand per buffer. Swizzle (both-sides,
// rule 21): phys_col16 = col16 ^ (row & 7); staging pre-swizzles the GLOBAL
// source column (LDS dest linear), ds_read applies the same XOR.
// ---------------------------------------------------------------------------
__global__ __launch_bounds__(256, 2) void gemm_fp8_blk(
    const unsigned char* __restrict__ Aq,   // [M][K] fp8
    const unsigned char* __restrict__ Bq,   // [N][K] fp8
    const float* __restrict__ xst,          // [K/128][M] act scales (transposed)
    const float* __restrict__ wsc,          // [N/128][K/128] weight scales
    float* __restrict__ C, int M, int N, int K) {
    __shared__ unsigned char As[2][16384];  // [buf][128 rows x 128 B]
    __shared__ unsigned char Bs[2][16384];
    __shared__ float Ss[2][128];            // act scales, 2-slot ring

    const int t    = threadIdx.x;
    const int lane = t & 63;
    const int wave = t >> 6;            // 0..3
    const int wr   = wave >> 1;         // wave row (0..1) -> rows wr*64
    const int wc   = wave & 1;          // wave col (0..1) -> cols wc*64
    const int bm   = blockIdx.y * 128;
    const int bn   = blockIdx.x * 128;

    // staging: 256 threads x 16B = 4KB = 32 rows x 128B per issue; 4/op/K-step
    const int srow   = t >> 3;          // 0..31
    const int scolsw = (((t & 7) ^ ((t >> 3) & 7)) << 4);   // pre-swizzled src col
    const unsigned char* gA = Aq + (size_t)(bm + srow) * K + scolsw;
    const unsigned char* gB = Bq + (size_t)(bn + srow) * K + scolsw;
    const float* gS = xst + bm + ((wave & 1) << 6) + lane;  // + kb*M per stage
    const int ldsoff = wave << 10;      // wave-uniform LDS base (+ lane*16 by HW)
    const int sSoff  = (wave & 1) << 8; // waves 2,3 duplicate 0,1 (same data)

    // fragment read addressing (swizzled): lane holds k = g*32 + 0..31
    const int r15 = lane & 15;
    const int g   = lane >> 4;                    // k-chunk 0..3
    const int km  = r15 & 7;                      // row swizzle key
    const int pc0 = (((2 * g) ^ km) << 4);        // first 16B unit
    const int pc1 = pc0 ^ 16;                     // second 16B unit
    const int aBase = (wr * 64 + r15) << 7;       // + m*2048 per frag
    const int bBase = (wc * 64 + r15) << 7;       // + n*2048 per frag
    const int ssB   = wr * 64 + (g << 2);         // float idx into Ss slot

    const float* wscp = wsc + ((bn >> 7) << 5);   // wave-uniform scale row

#define STG_A(BUF, KB, I)                                                       \
    __builtin_amdgcn_global_load_lds(                                           \
        (const AS1 void*)(gA + (size_t)(I) * 32 * K + ((size_t)(KB) << 7)),     \
        (AS3 void*)(&As[BUF][0] + (I) * 4096 + ldsoff), 16, 0, 0)
#define STG_B(BUF, KB, I)                                                       \
    __builtin_amdgcn_global_load_lds(                                           \
        (const AS1 void*)(gB + (size_t)(I) * 32 * K + ((size_t)(KB) << 7)),     \
        (AS3 void*)(&Bs[BUF][0] + (I) * 4096 + ldsoff), 16, 0, 0)
#define STG_S(KB)                                                               \
    __builtin_amdgcn_global_load_lds(                                           \
        (const AS1 void*)(gS + (size_t)(KB) * M),                               \
        (AS3 void*)((unsigned char*)&Ss[(KB) & 1][0] + sSoff), 4, 0, 0)
#define VMCNT0() asm volatile("s_waitcnt vmcnt(0)" ::: "memory")

#define RD8(PTR, RB) ({                                                         \
    i32x4 lo_ = *(const i32x4*)((PTR) + (RB) + pc0);                            \
    i32x4 hi_ = *(const i32x4*)((PTR) + (RB) + pc1);                            \
    __builtin_shufflevector(lo_, hi_, 0, 1, 2, 3, 4, 5, 6, 7); })

    f32x4 accM[4][4] = {};
    const f32x4 z4 = {0.f, 0.f, 0.f, 0.f};

    // prologue: stage K-step 0 (scale + 4A + 4B), drain, sync.
    STG_S(0);
#pragma unroll
    for (int i = 0; i < 4; ++i) { STG_A(0, 0, i); STG_B(0, 0, i); }
    VMCNT0();
    __builtin_amdgcn_s_barrier();
    asm volatile("" ::: "memory");

#pragma unroll 1
    for (int kb = 0; kb < 32; ++kb) {
        const int buf = kb & 1;
        const float wsv = wscp[kb];
        const unsigned char* ap = &As[buf][0];
        const unsigned char* bp = &Bs[buf][0];
        const float* sp = &Ss[buf][0];

        i32x8 pb[4], pa[4];
        f32x4 sc[4];
#pragma unroll
        for (int n = 0; n < 4; ++n) pb[n] = RD8(bp, bBase + (n << 11));
#pragma unroll
        for (int m = 0; m < 4; ++m) {
            pa[m] = RD8(ap, aBase + (m << 11));
            sc[m] = (*(const f32x4*)(sp + ssB + (m << 4))) * wsv;
        }
        // stage next K-step (8 data + 1 scale); lands under this step's compute
        if (kb < 31) {
            STG_S(kb + 1);
#pragma unroll
            for (int i = 0; i < 4; ++i) { STG_A(buf ^ 1, kb + 1, i); STG_B(buf ^ 1, kb + 1, i); }
        }
        __builtin_amdgcn_s_setprio(1);
        f32x4 q[4][4];
#pragma unroll
        for (int m = 0; m < 4; ++m)
#pragma unroll
            for (int n = 0; n < 4; ++n)
                q[m][n] = __builtin_amdgcn_mfma_scale_f32_16x16x128_f8f6f4(
                    pa[m], pb[n], z4, 0, 0,
                    0, 0x7F7F7F7F,                // scale A = 1.0 (e8m0 127)
                    0, 0x7F7F7F7F);               // scale B = 1.0
        __builtin_amdgcn_s_setprio(0);
#pragma unroll
        for (int m = 0; m < 4; ++m)
#pragma unroll
            for (int n = 0; n < 4; ++n)
                accM[m][n] += q[m][n] * sc[m];

        VMCNT0();                      // staged loads for kb+1 have landed
        __builtin_amdgcn_s_barrier();  // everyone done reading buf
        asm volatile("" ::: "memory");
    }

    // C write: row = g*4 + reg within frag, col = r15 (verified C/D layout)
    const int cm = bm + wr * 64 + (g << 2);
    const int cn = bn + wc * 64 + r15;
#pragma unroll
    for (int m = 0; m < 4; ++m)
#pragma unroll
        for (int n = 0; n < 4; ++n) {
            float* cp = C + (size_t)(cm + m * 16) * N + (cn + n * 16);
#pragma unroll
            for (int r = 0; r < 4; ++r) cp[(size_t)r * N] = accM[m][n][r];
        }
#undef STG_A
#undef STG_B
#undef STG_S
#undef VMCNT0
#undef RD8
}

extern "C" void kernel_launch(void* const* d_in, const int* in_sizes, int n_in,
                              void* d_out, int out_size, void* d_ws, size_t ws_size,
                              hipStream_t stream) {
    const float* x   = (const float*)d_in[0];   // [4096][4096] fp32
    const float* wqf = (const float*)d_in[1];   // [4096][4096] fp32 (fp8-grid values)
    const float* wsc = (const float*)d_in[2];   // [32][32] fp32
    float* out = (float*)d_out;

    const int M = 4096, N = 4096, K = 4096;

    unsigned char* xq  = (unsigned char*)d_ws;                       // 16 MB
    unsigned char* wq8 = (unsigned char*)d_ws + (size_t)M * K;       // 16 MB
    float* xst = (float*)((unsigned char*)d_ws + (size_t)M * K + (size_t)N * K); // 512 KB

    act_quant_k<<<M * (K / 128) / 8, 256, 0, stream>>>(x, xq, xst, M, K);
    wq_cvt_k<<<(N / 4) * (K / 256), 256, 0, stream>>>(wqf, wq8);
    dim3 grid(N / 128, M / 128);
    gemm_fp8_blk<<<grid, 256, 0, stream>>>(xq, wq8, xst, wsc, out, M, N, K);
}